// Round 5
// baseline (2951.587 us; speedup 1.0000x reference)
//
#include <hip/hip_runtime.h>

#define NP 50000
#define NL 10000
#define PLEN 5
#define NE (NP * PLEN)
#define DD 32
#define RUU 256
#define TITERS 8

__device__ __forceinline__ float sigmoidf_(float a) {
    return 1.0f / (1.0f + __expf(-a));
}
__device__ __forceinline__ float tanhf_(float a) {
    a = fminf(fmaxf(a, -15.0f), 15.0f);
    float t = __expf(2.0f * a);
    return (t - 1.0f) / (t + 1.0f);
}

__global__ __launch_bounds__(256) void k_init(
    const float* __restrict__ traffic, const float* __restrict__ packets,
    const float* __restrict__ tdp, const float* __restrict__ capacity,
    float* __restrict__ path_state, float* __restrict__ link_state,
    float* __restrict__ path_sum, int* __restrict__ lens) {
    int i = blockIdx.x * 256 + threadIdx.x;
    if (i < NP) {
        float v[DD];
        v[0] = traffic[i];
        v[1] = packets[i];
#pragma unroll
        for (int k = 0; k < 12; k++) v[2 + k] = tdp[i * 12 + k];
#pragma unroll
        for (int k = 14; k < DD; k++) v[k] = 0.0f;
#pragma unroll
        for (int k = 0; k < DD; k++) path_state[i * DD + k] = v[k];
        lens[i] = 0;
    }
    if (i < NL) {
        link_state[i * DD] = capacity[i];
#pragma unroll
        for (int k = 1; k < DD; k++) link_state[i * DD + k] = 0.0f;
#pragma unroll
        for (int k = 0; k < DD; k++) path_sum[i * DD + k] = 0.0f;
    }
}

__global__ __launch_bounds__(256) void k_lens(const int* __restrict__ path_ids,
                                              const int* __restrict__ seq_path,
                                              int* __restrict__ lens) {
    int e = blockIdx.x * 256 + threadIdx.x;
    if (e < NE) atomicMax(&lens[path_ids[e]], seq_path[e] + 1);
}

// Wave = 1 path. lane -> (d = lane&31 output dim, half = lane>>5 k-chunk).
// Weights in registers (96 VGPR/lane), h redistribution via 128B wave-private
// LDS (1 ds_write + 4 broadcast ds_read_b128 per step). x software-pipelined.
__global__ __launch_bounds__(256, 2) void k_gru_paths(
    const float* __restrict__ link_state, float* __restrict__ path_state,
    const int* __restrict__ link_to_path, const int* __restrict__ lens,
    const float* __restrict__ Wi, const float* __restrict__ Wh,
    const float* __restrict__ bi, const float* __restrict__ bh) {
    __shared__ float hbuf[4][DD];
    const int tid = threadIdx.x;
    const int wave = tid >> 6;
    const int lane = tid & 63;
    const int d = lane & 31;
    const int half = lane >> 5;
    const int p = blockIdx.x * 4 + wave;   // grid = NP/4 exactly

    float wi[3][16], wh[3][16];
#pragma unroll
    for (int g = 0; g < 3; g++) {
        const float* wip = &Wi[(g * 32 + d) * 32 + half * 16];
        const float* whp = &Wh[(g * 32 + d) * 32 + half * 16];
#pragma unroll
        for (int c = 0; c < 4; c++) {
            *(float4*)&wi[g][c * 4] = *(const float4*)&wip[c * 4];
            *(float4*)&wh[g][c * 4] = *(const float4*)&whp[c * 4];
        }
    }
    const float bir = bi[d], biz = bi[d + 32], bin = bi[d + 64];
    const float bhr = bh[d], bhz = bh[d + 32], bhn = bh[d + 64];

    float hd = path_state[p * DD + d];
    float hk[16];
#pragma unroll
    for (int c = 0; c < 4; c++)
        *(float4*)&hk[c * 4] = *(const float4*)&path_state[p * DD + half * 16 + c * 4];

    const int len = lens[p];
    int li[PLEN];
#pragma unroll
    for (int s = 0; s < PLEN; s++) li[s] = link_to_path[p * PLEN + s];

    float xk[16];
#pragma unroll
    for (int c = 0; c < 4; c++)
        *(float4*)&xk[c * 4] = *(const float4*)&link_state[li[0] * DD + half * 16 + c * 4];

#pragma unroll
    for (int st = 0; st < PLEN; st++) {
        float xn[16];
        if (st + 1 < PLEN) {
#pragma unroll
            for (int c = 0; c < 4; c++)
                *(float4*)&xn[c * 4] =
                    *(const float4*)&link_state[li[st + 1] * DD + half * 16 + c * 4];
        }
        float ir = 0.f, iz = 0.f, in_ = 0.f, hr = 0.f, hz = 0.f, hn = 0.f;
#pragma unroll
        for (int k = 0; k < 16; k++) {
            ir  = fmaf(xk[k], wi[0][k], ir);
            iz  = fmaf(xk[k], wi[1][k], iz);
            in_ = fmaf(xk[k], wi[2][k], in_);
            hr  = fmaf(hk[k], wh[0][k], hr);
            hz  = fmaf(hk[k], wh[1][k], hz);
            hn  = fmaf(hk[k], wh[2][k], hn);
        }
        ir += __shfl_xor(ir, 32);
        iz += __shfl_xor(iz, 32);
        in_ += __shfl_xor(in_, 32);
        hr += __shfl_xor(hr, 32);
        hz += __shfl_xor(hz, 32);
        hn += __shfl_xor(hn, 32);
        float r = sigmoidf_(ir + bir + hr + bhr);
        float z = sigmoidf_(iz + biz + hz + bhz);
        float n = tanhf_(in_ + bin + r * (hn + bhn));
        float hnew = (1.0f - z) * n + z * hd;
        hd = (st < len) ? hnew : hd;   // pack_padded semantics
        // wave-private redistribution: both halves write same value (benign)
        hbuf[wave][d] = hd;
#pragma unroll
        for (int c = 0; c < 4; c++)
            *(float4*)&hk[c * 4] = *(const float4*)&hbuf[wave][half * 16 + c * 4];
        if (st + 1 < PLEN) {
#pragma unroll
            for (int k = 0; k < 16; k++) xk[k] = xn[k];
        }
    }
    if (half == 0) path_state[p * DD + d] = hd;
}

__global__ __launch_bounds__(256) void k_scatter(
    const float* __restrict__ path_state, const int* __restrict__ path_to_link,
    const int* __restrict__ seq_links, float* __restrict__ path_sum) {
    int idx = blockIdx.x * 256 + threadIdx.x;
    if (idx >= NE * 8) return;
    int e = idx >> 3;
    int d0 = (idx & 7) * 4;
    int p = path_to_link[e];
    int l = seq_links[e];
    float4 v = *(const float4*)&path_state[p * DD + d0];
    atomicAdd(&path_sum[l * DD + d0 + 0], v.x);
    atomicAdd(&path_sum[l * DD + d0 + 1], v.y);
    atomicAdd(&path_sum[l * DD + d0 + 2], v.z);
    atomicAdd(&path_sum[l * DD + d0 + 3], v.w);
}

// Wave = 1 link, single GRU step, register weights; zeroes path_sum after use.
__global__ __launch_bounds__(256, 2) void k_gru_links(
    float* __restrict__ path_sum, float* __restrict__ link_state,
    const float* __restrict__ Wi, const float* __restrict__ Wh,
    const float* __restrict__ bi, const float* __restrict__ bh) {
    const int tid = threadIdx.x;
    const int wave = tid >> 6;
    const int lane = tid & 63;
    const int d = lane & 31;
    const int half = lane >> 5;
    const int i = blockIdx.x * 4 + wave;   // grid = NL/4 exactly

    float wi[3][16], wh[3][16];
#pragma unroll
    for (int g = 0; g < 3; g++) {
        const float* wip = &Wi[(g * 32 + d) * 32 + half * 16];
        const float* whp = &Wh[(g * 32 + d) * 32 + half * 16];
#pragma unroll
        for (int c = 0; c < 4; c++) {
            *(float4*)&wi[g][c * 4] = *(const float4*)&wip[c * 4];
            *(float4*)&wh[g][c * 4] = *(const float4*)&whp[c * 4];
        }
    }
    const float bir = bi[d], biz = bi[d + 32], bin = bi[d + 64];
    const float bhr = bh[d], bhz = bh[d + 32], bhn = bh[d + 64];

    float hd = link_state[i * DD + d];
    float hk[16], xk[16];
#pragma unroll
    for (int c = 0; c < 4; c++) {
        *(float4*)&hk[c * 4] = *(const float4*)&link_state[i * DD + half * 16 + c * 4];
        *(float4*)&xk[c * 4] = *(const float4*)&path_sum[i * DD + half * 16 + c * 4];
    }
    float ir = 0.f, iz = 0.f, in_ = 0.f, hr = 0.f, hz = 0.f, hn = 0.f;
#pragma unroll
    for (int k = 0; k < 16; k++) {
        ir  = fmaf(xk[k], wi[0][k], ir);
        iz  = fmaf(xk[k], wi[1][k], iz);
        in_ = fmaf(xk[k], wi[2][k], in_);
        hr  = fmaf(hk[k], wh[0][k], hr);
        hz  = fmaf(hk[k], wh[1][k], hz);
        hn  = fmaf(hk[k], wh[2][k], hn);
    }
    ir += __shfl_xor(ir, 32);
    iz += __shfl_xor(iz, 32);
    in_ += __shfl_xor(in_, 32);
    hr += __shfl_xor(hr, 32);
    hz += __shfl_xor(hz, 32);
    hn += __shfl_xor(hn, 32);
    float r = sigmoidf_(ir + bir + hr + bhr);
    float z = sigmoidf_(iz + biz + hz + bhz);
    float n = tanhf_(in_ + bin + r * (hn + bhn));
    float hnew = (1.0f - z) * n + z * hd;
    if (half == 0) {
        link_state[i * DD + d] = hnew;
        path_sum[i * DD + d] = 0.0f;   // ready for next iteration's scatter
    }
}

// Readout: 64 paths/block, 256 threads. Register-tiled 8x8 GEMM vs W2 staged
// in XOR-swizzled 32KB k-slabs. LDS = 64KB sr1 + 32KB slab + 8KB sps/red.
__global__ __launch_bounds__(256, 2) void k_readout(
    const float* __restrict__ path_state, float* __restrict__ out,
    const float* __restrict__ W1, const float* __restrict__ b1,
    const float* __restrict__ W2, const float* __restrict__ b2,
    const float* __restrict__ W3, const float* __restrict__ b3) {
    __shared__ float sr1[64 * RUU];      // 64 KB
    __shared__ float sw[RUU * 32];       // 32 KB (xor-swizzled W2 slab)
    __shared__ float sred[64 * 32];      // 8 KB (sps tile, then partials)
    const int tid = threadIdx.x;
    const int p0 = blockIdx.x * 64;

    // stage path_state tile [64][32] into sred
    {
        float4* dst = (float4*)sred;
#pragma unroll
        for (int r = 0; r < 2; r++) {
            int gidx = r * 256 + tid;          // 512 float4
            int row = gidx >> 3, f4 = gidx & 7;
            int p = p0 + row;
            if (p >= NP) p = NP - 1;
            dst[gidx] = *(const float4*)&path_state[(size_t)p * DD + f4 * 4];
        }
    }
    // W1 row of column tid into registers: 32 floats = 8 float4 (fixed: was 4)
    float w1r[DD];
#pragma unroll
    for (int c = 0; c < 8; c++)
        *(float4*)&w1r[c * 4] = *(const float4*)&W1[tid * DD + c * 4];
    float bb1 = b1[tid];
    __syncthreads();

    // phase 1: r1[m][tid] (sps reads are wave-uniform broadcasts)
    for (int m = 0; m < 64; m++) {
        float acc = bb1;
        const float4* xr = (const float4*)&sred[m * DD];
#pragma unroll
        for (int c = 0; c < 8; c++) {
            float4 xv = xr[c];
            acc = fmaf(xv.x, w1r[c * 4 + 0], fmaf(xv.y, w1r[c * 4 + 1],
                  fmaf(xv.z, w1r[c * 4 + 2], fmaf(xv.w, w1r[c * 4 + 3], acc))));
        }
        sr1[m * RUU + tid] = fmaxf(acc, 0.0f);
    }

    // phase 2: C[64x256] = sr1 @ W2^T, thread tile 8 paths x 8 cols
    const int pig = tid >> 5;      // 8 groups x 8 paths
    const int jg  = tid & 31;      // 32 groups x 8 cols
    float accs[8][8];
#pragma unroll
    for (int jj = 0; jj < 8; jj++) {
        float bv = b2[jg * 8 + jj];
#pragma unroll
        for (int pp = 0; pp < 8; pp++) accs[pp][jj] = bv;
    }
    for (int s = 0; s < 8; s++) {
        __syncthreads();
#pragma unroll
        for (int r = 0; r < 8; r++) {
            int gidx = r * 256 + tid;          // 2048 float4
            int j = gidx >> 3, kk = gidx & 7;
            float4 v = *(const float4*)&W2[j * RUU + s * 32 + kk * 4];
            ((float4*)sw)[j * 8 + (kk ^ ((j >> 3) & 7))] = v;
        }
        __syncthreads();
        for (int k4 = 0; k4 < 8; k4++) {
            float a[8][4];
#pragma unroll
            for (int pp = 0; pp < 8; pp++)
                *(float4*)&a[pp][0] =
                    *(const float4*)&sr1[(pig * 8 + pp) * RUU + s * 32 + k4 * 4];
#pragma unroll
            for (int jj = 0; jj < 8; jj++) {
                float4 w = ((const float4*)sw)[(jg * 8 + jj) * 8 + (k4 ^ (jg & 7))];
#pragma unroll
                for (int pp = 0; pp < 8; pp++) {
                    accs[pp][jj] = fmaf(a[pp][0], w.x, fmaf(a[pp][1], w.y,
                                   fmaf(a[pp][2], w.z, fmaf(a[pp][3], w.w, accs[pp][jj]))));
                }
            }
        }
    }

    // epilogue: relu, dot with W3, reduce over jg
    float w3r[8];
#pragma unroll
    for (int c = 0; c < 2; c++)
        *(float4*)&w3r[c * 4] = *(const float4*)&W3[jg * 8 + c * 4];
#pragma unroll
    for (int pp = 0; pp < 8; pp++) {
        float v = 0.f;
#pragma unroll
        for (int jj = 0; jj < 8; jj++) v = fmaf(w3r[jj], fmaxf(accs[pp][jj], 0.f), v);
        sred[(pig * 8 + pp) * 32 + jg] = v;
    }
    __syncthreads();
    if (tid < 64) {
        float v = b3[0];
        const float* sp = &sred[tid * 32];
#pragma unroll
        for (int g = 0; g < 32; g++) v += sp[g];
        int p = p0 + tid;
        if (p < NP) out[p] = v;
    }
}

extern "C" void kernel_launch(void* const* d_in, const int* in_sizes, int n_in,
                              void* d_out, int out_size, void* d_ws, size_t ws_size,
                              hipStream_t stream) {
    const float* traffic  = (const float*)d_in[0];
    const float* packets  = (const float*)d_in[1];
    const float* tdp      = (const float*)d_in[2];
    const float* capacity = (const float*)d_in[3];
    const int* link_to_path = (const int*)d_in[4];
    const int* path_ids     = (const int*)d_in[5];
    const int* seq_path     = (const int*)d_in[6];
    const int* path_to_link = (const int*)d_in[7];
    const int* seq_links    = (const int*)d_in[8];
    const float* Wi_p = (const float*)d_in[11];
    const float* Wh_p = (const float*)d_in[12];
    const float* bi_p = (const float*)d_in[13];
    const float* bh_p = (const float*)d_in[14];
    const float* Wi_l = (const float*)d_in[15];
    const float* Wh_l = (const float*)d_in[16];
    const float* bi_l = (const float*)d_in[17];
    const float* bh_l = (const float*)d_in[18];
    const float* W1 = (const float*)d_in[19];
    const float* b1 = (const float*)d_in[20];
    const float* W2 = (const float*)d_in[21];
    const float* b2 = (const float*)d_in[22];
    const float* W3 = (const float*)d_in[23];
    const float* b3 = (const float*)d_in[24];
    float* out = (float*)d_out;

    float* path_state = (float*)d_ws;                  // NP*32 f32
    float* link_state = path_state + (size_t)NP * DD;  // NL*32
    float* path_sum   = link_state + (size_t)NL * DD;  // NL*32
    int*   lens       = (int*)(path_sum + (size_t)NL * DD);  // NP ints

    k_init<<<(NP + 255) / 256, 256, 0, stream>>>(traffic, packets, tdp, capacity,
                                                 path_state, link_state, path_sum, lens);
    k_lens<<<(NE + 255) / 256, 256, 0, stream>>>(path_ids, seq_path, lens);
    for (int t = 0; t < TITERS; t++) {
        k_gru_paths<<<NP / 4, 256, 0, stream>>>(
            link_state, path_state, link_to_path, lens, Wi_p, Wh_p, bi_p, bh_p);
        k_scatter<<<(NE * 8 + 255) / 256, 256, 0, stream>>>(
            path_state, path_to_link, seq_links, path_sum);
        k_gru_links<<<NL / 4, 256, 0, stream>>>(
            path_sum, link_state, Wi_l, Wh_l, bi_l, bh_l);
    }
    k_readout<<<(NP + 63) / 64, 256, 0, stream>>>(path_state, out, W1, b1, W2,
                                                  b2, W3, b3);
}

// Round 6
// 1548.983 us; speedup vs baseline: 1.9055x; 1.9055x over previous
//
#include <hip/hip_runtime.h>

#define NP 50000
#define NL 10000
#define PLEN 5
#define NE (NP * PLEN)
#define DD 32
#define RUU 256
#define TITERS 8
#define PPW 8   /* paths (or links) per wave */

__device__ __forceinline__ float sigmoidf_(float a) {
    return 1.0f / (1.0f + __expf(-a));
}
__device__ __forceinline__ float tanhf_(float a) {
    a = fminf(fmaxf(a, -15.0f), 15.0f);
    float t = __expf(2.0f * a);
    return (t - 1.0f) / (t + 1.0f);
}

__global__ __launch_bounds__(256) void k_init(
    const float* __restrict__ traffic, const float* __restrict__ packets,
    const float* __restrict__ tdp, const float* __restrict__ capacity,
    float* __restrict__ path_state, float* __restrict__ link_state,
    int* __restrict__ lens, int* __restrict__ cnt) {
    int i = blockIdx.x * 256 + threadIdx.x;
    if (i < NP) {
        float v[DD];
        v[0] = traffic[i];
        v[1] = packets[i];
#pragma unroll
        for (int k = 0; k < 12; k++) v[2 + k] = tdp[i * 12 + k];
#pragma unroll
        for (int k = 14; k < DD; k++) v[k] = 0.0f;
#pragma unroll
        for (int k = 0; k < DD; k++) path_state[i * DD + k] = v[k];
        lens[i] = 0;
    }
    if (i < NL) {
        link_state[i * DD] = capacity[i];
#pragma unroll
        for (int k = 1; k < DD; k++) link_state[i * DD + k] = 0.0f;
        cnt[i] = 0;
    }
}

__global__ __launch_bounds__(256) void k_lens(const int* __restrict__ path_ids,
                                              const int* __restrict__ seq_path,
                                              int* __restrict__ lens) {
    int e = blockIdx.x * 256 + threadIdx.x;
    if (e < NE) atomicMax(&lens[path_ids[e]], seq_path[e] + 1);
}

__global__ __launch_bounds__(256) void k_csr_count(const int* __restrict__ seq_links,
                                                   int* __restrict__ cnt) {
    int e = blockIdx.x * 256 + threadIdx.x;
    if (e < NE) atomicAdd(&cnt[seq_links[e]], 1);
}

// single block: exclusive scan of cnt[NL] -> offs[NL+1]; cursor = offs copy
__global__ __launch_bounds__(256) void k_csr_scan(const int* __restrict__ cnt,
                                                  int* __restrict__ offs,
                                                  int* __restrict__ cursor) {
    __shared__ int ssum[256];
    const int tid = threadIdx.x;
    const int CH = 40;  // 256*40 >= NL
    int base = tid * CH;
    int s = 0;
    for (int i = 0; i < CH; i++) {
        int idx = base + i;
        s += (idx < NL) ? cnt[idx] : 0;
    }
    ssum[tid] = s;
    __syncthreads();
    for (int off = 1; off < 256; off <<= 1) {
        int t = (tid >= off) ? ssum[tid - off] : 0;
        __syncthreads();
        ssum[tid] += t;
        __syncthreads();
    }
    int run = ssum[tid] - s;  // exclusive prefix of this chunk
    for (int i = 0; i < CH; i++) {
        int idx = base + i;
        if (idx < NL) {
            offs[idx] = run;
            cursor[idx] = run;
            run += cnt[idx];
        }
    }
    if (tid == 0) offs[NL] = ssum[255];
}

__global__ __launch_bounds__(256) void k_csr_fill(const int* __restrict__ seq_links,
                                                  const int* __restrict__ path_to_link,
                                                  int* __restrict__ cursor,
                                                  int* __restrict__ csr_pids) {
    int e = blockIdx.x * 256 + threadIdx.x;
    if (e < NE) {
        int l = seq_links[e];
        int slot = atomicAdd(&cursor[l], 1);  // absolute index (cursor=offs init)
        csr_pids[slot] = path_to_link[e];
    }
}

// Wave = 1 path, PPW paths per wave. lane -> (d = lane&31, half = lane>>5).
// Weights pinned in VGPRs (asm) so the compiler cannot re-load them per step.
__global__ __launch_bounds__(256, 2) void k_gru_paths(
    const float* __restrict__ link_state, float* __restrict__ path_state,
    const int* __restrict__ link_to_path, const int* __restrict__ lens,
    const float* __restrict__ Wi, const float* __restrict__ Wh,
    const float* __restrict__ bi, const float* __restrict__ bh) {
    __shared__ float hbuf[4][DD];
    const int tid = threadIdx.x;
    const int wave = tid >> 6;
    const int lane = tid & 63;
    const int d = lane & 31;
    const int half = lane >> 5;

    float wi[3][16], wh[3][16];
#pragma unroll
    for (int g = 0; g < 3; g++) {
        const float* wip = &Wi[(g * 32 + d) * 32 + half * 16];
        const float* whp = &Wh[(g * 32 + d) * 32 + half * 16];
#pragma unroll
        for (int c = 0; c < 4; c++) {
            *(float4*)&wi[g][c * 4] = *(const float4*)&wip[c * 4];
            *(float4*)&wh[g][c * 4] = *(const float4*)&whp[c * 4];
        }
    }
#pragma unroll
    for (int g = 0; g < 3; g++)
#pragma unroll
        for (int k = 0; k < 16; k++) {
            asm volatile("" : "+v"(wi[g][k]));
            asm volatile("" : "+v"(wh[g][k]));
        }
    const float bir = bi[d], biz = bi[d + 32], bin = bi[d + 64];
    const float bhr = bh[d], bhz = bh[d + 32], bhn = bh[d + 64];

    const int pbase = (blockIdx.x * 4 + wave) * PPW;
    for (int pp = 0; pp < PPW; pp++) {
        const int p = pbase + pp;
        if (p >= NP) break;

        float hd = path_state[p * DD + d];
        float hk[16];
#pragma unroll
        for (int c = 0; c < 4; c++)
            *(float4*)&hk[c * 4] = *(const float4*)&path_state[p * DD + half * 16 + c * 4];

        const int len = lens[p];
        int li[PLEN];
#pragma unroll
        for (int s = 0; s < PLEN; s++) li[s] = link_to_path[p * PLEN + s];

        float xk[16];
#pragma unroll
        for (int c = 0; c < 4; c++)
            *(float4*)&xk[c * 4] = *(const float4*)&link_state[li[0] * DD + half * 16 + c * 4];

#pragma unroll
        for (int st = 0; st < PLEN; st++) {
            float xn[16];
            if (st + 1 < PLEN) {
#pragma unroll
                for (int c = 0; c < 4; c++)
                    *(float4*)&xn[c * 4] =
                        *(const float4*)&link_state[li[st + 1] * DD + half * 16 + c * 4];
            }
            float ir = 0.f, iz = 0.f, in_ = 0.f, hr = 0.f, hz = 0.f, hn = 0.f;
#pragma unroll
            for (int k = 0; k < 16; k++) {
                ir  = fmaf(xk[k], wi[0][k], ir);
                iz  = fmaf(xk[k], wi[1][k], iz);
                in_ = fmaf(xk[k], wi[2][k], in_);
                hr  = fmaf(hk[k], wh[0][k], hr);
                hz  = fmaf(hk[k], wh[1][k], hz);
                hn  = fmaf(hk[k], wh[2][k], hn);
            }
            ir += __shfl_xor(ir, 32);
            iz += __shfl_xor(iz, 32);
            in_ += __shfl_xor(in_, 32);
            hr += __shfl_xor(hr, 32);
            hz += __shfl_xor(hz, 32);
            hn += __shfl_xor(hn, 32);
            float r = sigmoidf_(ir + bir + hr + bhr);
            float z = sigmoidf_(iz + biz + hz + bhz);
            float n = tanhf_(in_ + bin + r * (hn + bhn));
            float hnew = (1.0f - z) * n + z * hd;
            hd = (st < len) ? hnew : hd;
            hbuf[wave][d] = hd;   // both halves write same value (2-way, free)
#pragma unroll
            for (int c = 0; c < 4; c++)
                *(float4*)&hk[c * 4] = *(const float4*)&hbuf[wave][half * 16 + c * 4];
            if (st + 1 < PLEN) {
#pragma unroll
                for (int k = 0; k < 16; k++) xk[k] = xn[k];
            }
        }
        if (half == 0) path_state[p * DD + d] = hd;
    }
}

// Fused gather + link GRU. Wave = 1 link (PPW links per wave).
// x = sum of path_state rows over the link's CSR edge list (halves split edges).
__global__ __launch_bounds__(256, 2) void k_links(
    const float* __restrict__ path_state, float* __restrict__ link_state,
    const int* __restrict__ offs, const int* __restrict__ csr_pids,
    const float* __restrict__ Wi, const float* __restrict__ Wh,
    const float* __restrict__ bi, const float* __restrict__ bh) {
    __shared__ float hbuf[4][DD];
    const int tid = threadIdx.x;
    const int wave = tid >> 6;
    const int lane = tid & 63;
    const int d = lane & 31;
    const int half = lane >> 5;

    float wi[3][16], wh[3][16];
#pragma unroll
    for (int g = 0; g < 3; g++) {
        const float* wip = &Wi[(g * 32 + d) * 32 + half * 16];
        const float* whp = &Wh[(g * 32 + d) * 32 + half * 16];
#pragma unroll
        for (int c = 0; c < 4; c++) {
            *(float4*)&wi[g][c * 4] = *(const float4*)&wip[c * 4];
            *(float4*)&wh[g][c * 4] = *(const float4*)&whp[c * 4];
        }
    }
#pragma unroll
    for (int g = 0; g < 3; g++)
#pragma unroll
        for (int k = 0; k < 16; k++) {
            asm volatile("" : "+v"(wi[g][k]));
            asm volatile("" : "+v"(wh[g][k]));
        }
    const float bir = bi[d], biz = bi[d + 32], bin = bi[d + 64];
    const float bhr = bh[d], bhz = bh[d + 32], bhn = bh[d + 64];

    const int lbase = (blockIdx.x * 4 + wave) * PPW;
    for (int ll = 0; ll < PPW; ll++) {
        const int l = lbase + ll;
        if (l >= NL) break;
        const int beg = offs[l], end = offs[l + 1];

        // gather: halves take alternating edges; pid load software-pipelined
        float xv = 0.f;
        int t = beg + half;
        int pid = (t < end) ? csr_pids[t] : 0;
        while (t < end) {
            int t2 = t + 2;
            int pid2 = (t2 < end) ? csr_pids[t2] : 0;
            xv += path_state[pid * DD + d];
            pid = pid2;
            t = t2;
        }
        xv += __shfl_xor(xv, 32);

        float hd = link_state[l * DD + d];
        float hk[16], xk[16];
#pragma unroll
        for (int c = 0; c < 4; c++)
            *(float4*)&hk[c * 4] = *(const float4*)&link_state[l * DD + half * 16 + c * 4];
        hbuf[wave][d] = xv;
#pragma unroll
        for (int c = 0; c < 4; c++)
            *(float4*)&xk[c * 4] = *(const float4*)&hbuf[wave][half * 16 + c * 4];

        float ir = 0.f, iz = 0.f, in_ = 0.f, hr = 0.f, hz = 0.f, hn = 0.f;
#pragma unroll
        for (int k = 0; k < 16; k++) {
            ir  = fmaf(xk[k], wi[0][k], ir);
            iz  = fmaf(xk[k], wi[1][k], iz);
            in_ = fmaf(xk[k], wi[2][k], in_);
            hr  = fmaf(hk[k], wh[0][k], hr);
            hz  = fmaf(hk[k], wh[1][k], hz);
            hn  = fmaf(hk[k], wh[2][k], hn);
        }
        ir += __shfl_xor(ir, 32);
        iz += __shfl_xor(iz, 32);
        in_ += __shfl_xor(in_, 32);
        hr += __shfl_xor(hr, 32);
        hz += __shfl_xor(hz, 32);
        hn += __shfl_xor(hn, 32);
        float r = sigmoidf_(ir + bir + hr + bhr);
        float z = sigmoidf_(iz + biz + hz + bhz);
        float n = tanhf_(in_ + bin + r * (hn + bhn));
        float hnew = (1.0f - z) * n + z * hd;
        if (half == 0) link_state[l * DD + d] = hnew;
    }
}

// Readout: 64 paths/block, 256 threads. Register-tiled 8x8 GEMM vs W2 staged
// in XOR-swizzled 32KB k-slabs. LDS = 64KB sr1 + 32KB slab + 8KB sps/red.
__global__ __launch_bounds__(256, 2) void k_readout(
    const float* __restrict__ path_state, float* __restrict__ out,
    const float* __restrict__ W1, const float* __restrict__ b1,
    const float* __restrict__ W2, const float* __restrict__ b2,
    const float* __restrict__ W3, const float* __restrict__ b3) {
    __shared__ float sr1[64 * RUU];      // 64 KB
    __shared__ float sw[RUU * 32];       // 32 KB (xor-swizzled W2 slab)
    __shared__ float sred[64 * 32];      // 8 KB (sps tile, then partials)
    const int tid = threadIdx.x;
    const int p0 = blockIdx.x * 64;

    {
        float4* dst = (float4*)sred;
#pragma unroll
        for (int r = 0; r < 2; r++) {
            int gidx = r * 256 + tid;          // 512 float4
            int row = gidx >> 3, f4 = gidx & 7;
            int p = p0 + row;
            if (p >= NP) p = NP - 1;
            dst[gidx] = *(const float4*)&path_state[(size_t)p * DD + f4 * 4];
        }
    }
    float w1r[DD];
#pragma unroll
    for (int c = 0; c < 8; c++)
        *(float4*)&w1r[c * 4] = *(const float4*)&W1[tid * DD + c * 4];
    float bb1 = b1[tid];
    __syncthreads();

    for (int m = 0; m < 64; m++) {
        float acc = bb1;
        const float4* xr = (const float4*)&sred[m * DD];
#pragma unroll
        for (int c = 0; c < 8; c++) {
            float4 xv = xr[c];
            acc = fmaf(xv.x, w1r[c * 4 + 0], fmaf(xv.y, w1r[c * 4 + 1],
                  fmaf(xv.z, w1r[c * 4 + 2], fmaf(xv.w, w1r[c * 4 + 3], acc))));
        }
        sr1[m * RUU + tid] = fmaxf(acc, 0.0f);
    }

    const int pig = tid >> 5;      // 8 groups x 8 paths
    const int jg  = tid & 31;      // 32 groups x 8 cols
    float accs[8][8];
#pragma unroll
    for (int jj = 0; jj < 8; jj++) {
        float bv = b2[jg * 8 + jj];
#pragma unroll
        for (int pp = 0; pp < 8; pp++) accs[pp][jj] = bv;
    }
    for (int s = 0; s < 8; s++) {
        __syncthreads();
#pragma unroll
        for (int r = 0; r < 8; r++) {
            int gidx = r * 256 + tid;          // 2048 float4
            int j = gidx >> 3, kk = gidx & 7;
            float4 v = *(const float4*)&W2[j * RUU + s * 32 + kk * 4];
            ((float4*)sw)[j * 8 + (kk ^ ((j >> 3) & 7))] = v;
        }
        __syncthreads();
        for (int k4 = 0; k4 < 8; k4++) {
            float a[8][4];
#pragma unroll
            for (int pp = 0; pp < 8; pp++)
                *(float4*)&a[pp][0] =
                    *(const float4*)&sr1[(pig * 8 + pp) * RUU + s * 32 + k4 * 4];
#pragma unroll
            for (int jj = 0; jj < 8; jj++) {
                float4 w = ((const float4*)sw)[(jg * 8 + jj) * 8 + (k4 ^ (jg & 7))];
#pragma unroll
                for (int pp = 0; pp < 8; pp++) {
                    accs[pp][jj] = fmaf(a[pp][0], w.x, fmaf(a[pp][1], w.y,
                                   fmaf(a[pp][2], w.z, fmaf(a[pp][3], w.w, accs[pp][jj]))));
                }
            }
        }
    }

    float w3r[8];
#pragma unroll
    for (int c = 0; c < 2; c++)
        *(float4*)&w3r[c * 4] = *(const float4*)&W3[jg * 8 + c * 4];
#pragma unroll
    for (int pp = 0; pp < 8; pp++) {
        float v = 0.f;
#pragma unroll
        for (int jj = 0; jj < 8; jj++) v = fmaf(w3r[jj], fmaxf(accs[pp][jj], 0.f), v);
        sred[(pig * 8 + pp) * 32 + jg] = v;
    }
    __syncthreads();
    if (tid < 64) {
        float v = b3[0];
        const float* sp = &sred[tid * 32];
#pragma unroll
        for (int g = 0; g < 32; g++) v += sp[g];
        int p = p0 + tid;
        if (p < NP) out[p] = v;
    }
}

extern "C" void kernel_launch(void* const* d_in, const int* in_sizes, int n_in,
                              void* d_out, int out_size, void* d_ws, size_t ws_size,
                              hipStream_t stream) {
    const float* traffic  = (const float*)d_in[0];
    const float* packets  = (const float*)d_in[1];
    const float* tdp      = (const float*)d_in[2];
    const float* capacity = (const float*)d_in[3];
    const int* link_to_path = (const int*)d_in[4];
    const int* path_ids     = (const int*)d_in[5];
    const int* seq_path     = (const int*)d_in[6];
    const int* path_to_link = (const int*)d_in[7];
    const int* seq_links    = (const int*)d_in[8];
    const float* Wi_p = (const float*)d_in[11];
    const float* Wh_p = (const float*)d_in[12];
    const float* bi_p = (const float*)d_in[13];
    const float* bh_p = (const float*)d_in[14];
    const float* Wi_l = (const float*)d_in[15];
    const float* Wh_l = (const float*)d_in[16];
    const float* bi_l = (const float*)d_in[17];
    const float* bh_l = (const float*)d_in[18];
    const float* W1 = (const float*)d_in[19];
    const float* b1 = (const float*)d_in[20];
    const float* W2 = (const float*)d_in[21];
    const float* b2 = (const float*)d_in[22];
    const float* W3 = (const float*)d_in[23];
    const float* b3 = (const float*)d_in[24];
    float* out = (float*)d_out;

    float* path_state = (float*)d_ws;                  // NP*32 f32
    float* link_state = path_state + (size_t)NP * DD;  // NL*32
    int* lens     = (int*)(link_state + (size_t)NL * DD);  // NP
    int* cnt      = lens + NP;                             // NL
    int* offs     = cnt + NL;                              // NL+1
    int* cursor   = offs + NL + 1;                         // NL
    int* csr_pids = cursor + NL;                           // NE

    k_init<<<(NP + 255) / 256, 256, 0, stream>>>(traffic, packets, tdp, capacity,
                                                 path_state, link_state, lens, cnt);
    k_lens<<<(NE + 255) / 256, 256, 0, stream>>>(path_ids, seq_path, lens);
    k_csr_count<<<(NE + 255) / 256, 256, 0, stream>>>(seq_links, cnt);
    k_csr_scan<<<1, 256, 0, stream>>>(cnt, offs, cursor);
    k_csr_fill<<<(NE + 255) / 256, 256, 0, stream>>>(seq_links, path_to_link,
                                                     cursor, csr_pids);
    for (int t = 0; t < TITERS; t++) {
        k_gru_paths<<<(NP + 4 * PPW - 1) / (4 * PPW), 256, 0, stream>>>(
            link_state, path_state, link_to_path, lens, Wi_p, Wh_p, bi_p, bh_p);
        k_links<<<(NL + 4 * PPW - 1) / (4 * PPW), 256, 0, stream>>>(
            path_state, link_state, offs, csr_pids, Wi_l, Wh_l, bi_l, bh_l);
    }
    k_readout<<<(NP + 63) / 64, 256, 0, stream>>>(path_state, out, W1, b1, W2,
                                                  b2, W3, b3);
}

// Round 7
// 1477.410 us; speedup vs baseline: 1.9978x; 1.0484x over previous
//
#include <hip/hip_runtime.h>

#define NP 50000
#define NL 10000
#define PLEN 5
#define NE (NP * PLEN)
#define DD 32
#define RUU 256
#define TITERS 8
#define PPW 8    /* paths per wave (path GRU) */
#define LPW 2    /* links per wave (link GRU) */

__device__ __forceinline__ float sigmoidf_(float a) {
    return 1.0f / (1.0f + __expf(-a));
}
__device__ __forceinline__ float tanhf_(float a) {
    a = fminf(fmaxf(a, -15.0f), 15.0f);
    float t = __expf(2.0f * a);
    return (t - 1.0f) / (t + 1.0f);
}

__global__ __launch_bounds__(256) void k_init(
    const float* __restrict__ traffic, const float* __restrict__ packets,
    const float* __restrict__ tdp, const float* __restrict__ capacity,
    float* __restrict__ path_state, float* __restrict__ link_state,
    int* __restrict__ lens, int* __restrict__ cnt) {
    int i = blockIdx.x * 256 + threadIdx.x;
    if (i < NP) {
        float v[DD];
        v[0] = traffic[i];
        v[1] = packets[i];
#pragma unroll
        for (int k = 0; k < 12; k++) v[2 + k] = tdp[i * 12 + k];
#pragma unroll
        for (int k = 14; k < DD; k++) v[k] = 0.0f;
#pragma unroll
        for (int k = 0; k < DD; k++) path_state[i * DD + k] = v[k];
        lens[i] = 0;
    }
    if (i < NL) {
        link_state[i * DD] = capacity[i];
#pragma unroll
        for (int k = 1; k < DD; k++) link_state[i * DD + k] = 0.0f;
        cnt[i] = 0;
    }
}

__global__ __launch_bounds__(256) void k_lens(const int* __restrict__ path_ids,
                                              const int* __restrict__ seq_path,
                                              int* __restrict__ lens) {
    int e = blockIdx.x * 256 + threadIdx.x;
    if (e < NE) atomicMax(&lens[path_ids[e]], seq_path[e] + 1);
}

__global__ __launch_bounds__(256) void k_csr_count(const int* __restrict__ seq_links,
                                                   int* __restrict__ cnt) {
    int e = blockIdx.x * 256 + threadIdx.x;
    if (e < NE) atomicAdd(&cnt[seq_links[e]], 1);
}

__global__ __launch_bounds__(256) void k_csr_scan(const int* __restrict__ cnt,
                                                  int* __restrict__ offs,
                                                  int* __restrict__ cursor) {
    __shared__ int ssum[256];
    const int tid = threadIdx.x;
    const int CH = 40;
    int base = tid * CH;
    int s = 0;
    for (int i = 0; i < CH; i++) {
        int idx = base + i;
        s += (idx < NL) ? cnt[idx] : 0;
    }
    ssum[tid] = s;
    __syncthreads();
    for (int off = 1; off < 256; off <<= 1) {
        int t = (tid >= off) ? ssum[tid - off] : 0;
        __syncthreads();
        ssum[tid] += t;
        __syncthreads();
    }
    int run = ssum[tid] - s;
    for (int i = 0; i < CH; i++) {
        int idx = base + i;
        if (idx < NL) {
            offs[idx] = run;
            cursor[idx] = run;
            run += cnt[idx];
        }
    }
    if (tid == 0) offs[NL] = ssum[255];
}

__global__ __launch_bounds__(256) void k_csr_fill(const int* __restrict__ seq_links,
                                                  const int* __restrict__ path_to_link,
                                                  int* __restrict__ cursor,
                                                  int* __restrict__ csr_pids) {
    int e = blockIdx.x * 256 + threadIdx.x;
    if (e < NE) {
        int l = seq_links[e];
        int slot = atomicAdd(&cursor[l], 1);
        csr_pids[slot] = path_to_link[e];
    }
}

// W2t[k][j] = W2[j][k]
__global__ __launch_bounds__(256) void k_w2t(const float* __restrict__ W2,
                                             float* __restrict__ W2t) {
    int j = blockIdx.x, k = threadIdx.x;
    W2t[k * RUU + j] = W2[j * RUU + k];
}

// Wave = 1 path, PPW paths per wave. lane -> (d = lane&31, half = lane>>5).
// Weights pinned in VGPRs; h redistribution via 16 ds_bpermute (no LDS).
__global__ __launch_bounds__(256, 2) void k_gru_paths(
    const float* __restrict__ link_state, float* __restrict__ path_state,
    const int* __restrict__ link_to_path, const int* __restrict__ lens,
    const float* __restrict__ Wi, const float* __restrict__ Wh,
    const float* __restrict__ bi, const float* __restrict__ bh) {
    const int tid = threadIdx.x;
    const int wave = tid >> 6;
    const int lane = tid & 63;
    const int d = lane & 31;
    const int half = lane >> 5;

    float wi[3][16], wh[3][16];
#pragma unroll
    for (int g = 0; g < 3; g++) {
        const float* wip = &Wi[(g * 32 + d) * 32 + half * 16];
        const float* whp = &Wh[(g * 32 + d) * 32 + half * 16];
#pragma unroll
        for (int c = 0; c < 4; c++) {
            *(float4*)&wi[g][c * 4] = *(const float4*)&wip[c * 4];
            *(float4*)&wh[g][c * 4] = *(const float4*)&whp[c * 4];
        }
    }
#pragma unroll
    for (int g = 0; g < 3; g++)
#pragma unroll
        for (int k = 0; k < 16; k++) {
            asm volatile("" : "+v"(wi[g][k]));
            asm volatile("" : "+v"(wh[g][k]));
        }
    const float bir = bi[d], biz = bi[d + 32], bin = bi[d + 64];
    const float bhr = bh[d], bhz = bh[d + 32], bhn = bh[d + 64];

    const int pbase = (blockIdx.x * 4 + wave) * PPW;
    for (int pp = 0; pp < PPW; pp++) {
        const int p = pbase + pp;
        if (p >= NP) break;

        float hd = path_state[p * DD + d];
        float hk[16];
#pragma unroll
        for (int c = 0; c < 4; c++)
            *(float4*)&hk[c * 4] = *(const float4*)&path_state[p * DD + half * 16 + c * 4];

        const int len = lens[p];
        int li[PLEN];
#pragma unroll
        for (int s = 0; s < PLEN; s++) li[s] = link_to_path[p * PLEN + s];

        float xk[16];
#pragma unroll
        for (int c = 0; c < 4; c++)
            *(float4*)&xk[c * 4] = *(const float4*)&link_state[li[0] * DD + half * 16 + c * 4];

#pragma unroll
        for (int st = 0; st < PLEN; st++) {
            float xn[16];
            if (st + 1 < PLEN) {
#pragma unroll
                for (int c = 0; c < 4; c++)
                    *(float4*)&xn[c * 4] =
                        *(const float4*)&link_state[li[st + 1] * DD + half * 16 + c * 4];
            }
            float ir = 0.f, iz = 0.f, in_ = 0.f, hr = 0.f, hz = 0.f, hn = 0.f;
#pragma unroll
            for (int k = 0; k < 16; k++) {
                ir  = fmaf(xk[k], wi[0][k], ir);
                iz  = fmaf(xk[k], wi[1][k], iz);
                in_ = fmaf(xk[k], wi[2][k], in_);
                hr  = fmaf(hk[k], wh[0][k], hr);
                hz  = fmaf(hk[k], wh[1][k], hz);
                hn  = fmaf(hk[k], wh[2][k], hn);
            }
            ir += __shfl_xor(ir, 32);
            iz += __shfl_xor(iz, 32);
            in_ += __shfl_xor(in_, 32);
            hr += __shfl_xor(hr, 32);
            hz += __shfl_xor(hz, 32);
            hn += __shfl_xor(hn, 32);
            float r = sigmoidf_(ir + bir + hr + bhr);
            float z = sigmoidf_(iz + biz + hz + bhz);
            float n = tanhf_(in_ + bin + r * (hn + bhn));
            float hnew = (1.0f - z) * n + z * hd;
            hd = (st < len) ? hnew : hd;
            // redistribute h via bpermute: hk[k] <- lane (half*16+k)'s hd
            int hdi = __float_as_int(hd);
#pragma unroll
            for (int k = 0; k < 16; k++) {
                int src = ((half << 4) + k) << 2;
                hk[k] = __int_as_float(__builtin_amdgcn_ds_bpermute(src, hdi));
            }
            if (st + 1 < PLEN) {
#pragma unroll
                for (int k = 0; k < 16; k++) xk[k] = xn[k];
            }
        }
        if (half == 0) path_state[p * DD + d] = hd;
    }
}

// Fused gather + link GRU. Wave = 1 link (LPW links per wave).
__global__ __launch_bounds__(256, 2) void k_links(
    const float* __restrict__ path_state, float* __restrict__ link_state,
    const int* __restrict__ offs, const int* __restrict__ csr_pids,
    const float* __restrict__ Wi, const float* __restrict__ Wh,
    const float* __restrict__ bi, const float* __restrict__ bh) {
    const int tid = threadIdx.x;
    const int wave = tid >> 6;
    const int lane = tid & 63;
    const int d = lane & 31;
    const int half = lane >> 5;

    float wi[3][16], wh[3][16];
#pragma unroll
    for (int g = 0; g < 3; g++) {
        const float* wip = &Wi[(g * 32 + d) * 32 + half * 16];
        const float* whp = &Wh[(g * 32 + d) * 32 + half * 16];
#pragma unroll
        for (int c = 0; c < 4; c++) {
            *(float4*)&wi[g][c * 4] = *(const float4*)&wip[c * 4];
            *(float4*)&wh[g][c * 4] = *(const float4*)&whp[c * 4];
        }
    }
#pragma unroll
    for (int g = 0; g < 3; g++)
#pragma unroll
        for (int k = 0; k < 16; k++) {
            asm volatile("" : "+v"(wi[g][k]));
            asm volatile("" : "+v"(wh[g][k]));
        }
    const float bir = bi[d], biz = bi[d + 32], bin = bi[d + 64];
    const float bhr = bh[d], bhz = bh[d + 32], bhn = bh[d + 64];

    const int lbase = (blockIdx.x * 4 + wave) * LPW;
    for (int ll = 0; ll < LPW; ll++) {
        const int l = lbase + ll;
        if (l >= NL) break;
        const int beg = offs[l], end = offs[l + 1];

        float xv = 0.f;
        int t = beg + half;
        int pid = (t < end) ? csr_pids[t] : 0;
        while (t < end) {
            int t2 = t + 2;
            int pid2 = (t2 < end) ? csr_pids[t2] : 0;
            xv += path_state[pid * DD + d];
            pid = pid2;
            t = t2;
        }
        xv += __shfl_xor(xv, 32);

        float hd = link_state[l * DD + d];
        float hk[16], xk[16];
#pragma unroll
        for (int c = 0; c < 4; c++)
            *(float4*)&hk[c * 4] = *(const float4*)&link_state[l * DD + half * 16 + c * 4];
        int xvi = __float_as_int(xv);
#pragma unroll
        for (int k = 0; k < 16; k++) {
            int src = ((half << 4) + k) << 2;
            xk[k] = __int_as_float(__builtin_amdgcn_ds_bpermute(src, xvi));
        }

        float ir = 0.f, iz = 0.f, in_ = 0.f, hr = 0.f, hz = 0.f, hn = 0.f;
#pragma unroll
        for (int k = 0; k < 16; k++) {
            ir  = fmaf(xk[k], wi[0][k], ir);
            iz  = fmaf(xk[k], wi[1][k], iz);
            in_ = fmaf(xk[k], wi[2][k], in_);
            hr  = fmaf(hk[k], wh[0][k], hr);
            hz  = fmaf(hk[k], wh[1][k], hz);
            hn  = fmaf(hk[k], wh[2][k], hn);
        }
        ir += __shfl_xor(ir, 32);
        iz += __shfl_xor(iz, 32);
        in_ += __shfl_xor(in_, 32);
        hr += __shfl_xor(hr, 32);
        hz += __shfl_xor(hz, 32);
        hn += __shfl_xor(hn, 32);
        float r = sigmoidf_(ir + bir + hr + bhr);
        float z = sigmoidf_(iz + biz + hz + bhz);
        float n = tanhf_(in_ + bin + r * (hn + bhn));
        float hnew = (1.0f - z) * n + z * hd;
        if (half == 0) link_state[l * DD + d] = hnew;
    }
}

// Readout: 64 paths/block. LDS = sr1 only (64KB) -> 2 blocks/CU.
// Phase1: path_state via wave-uniform global broadcasts; W1 row in regs.
// Phase2: a from sr1 (2-address LDS broadcast), W2 from pre-transposed W2t
// (coalesced 1KB global loads, L1/L2-resident). Epilogue: shfl reduce.
__global__ __launch_bounds__(256, 2) void k_readout(
    const float* __restrict__ path_state, float* __restrict__ out,
    const float* __restrict__ W1, const float* __restrict__ b1,
    const float* __restrict__ W2t, const float* __restrict__ b2,
    const float* __restrict__ W3, const float* __restrict__ b3) {
    __shared__ float sr1[64 * RUU];      // 64 KB
    const int tid = threadIdx.x;
    const int p0 = blockIdx.x * 64;

    float w1r[DD];
#pragma unroll
    for (int c = 0; c < 8; c++)
        *(float4*)&w1r[c * 4] = *(const float4*)&W1[tid * DD + c * 4];
    float bb1 = b1[tid];

    // phase 1
#pragma unroll 2
    for (int m = 0; m < 64; m++) {
        int p = p0 + m;
        if (p >= NP) p = NP - 1;
        const float4* xr = (const float4*)&path_state[(size_t)p * DD];
        float acc = bb1;
#pragma unroll
        for (int c = 0; c < 8; c++) {
            float4 xv = xr[c];
            acc = fmaf(xv.x, w1r[c * 4 + 0], fmaf(xv.y, w1r[c * 4 + 1],
                  fmaf(xv.z, w1r[c * 4 + 2], fmaf(xv.w, w1r[c * 4 + 3], acc))));
        }
        sr1[m * RUU + tid] = fmaxf(acc, 0.0f);
    }
    __syncthreads();

    // phase 2: thread (pig = tid>>5, jg = tid&31) -> 8 paths x 8 cols
    const int pig = tid >> 5;
    const int jg  = tid & 31;
    float accs[8][8];
#pragma unroll
    for (int jj = 0; jj < 8; jj++) {
        float bv = b2[jg * 8 + jj];
#pragma unroll
        for (int pp = 0; pp < 8; pp++) accs[pp][jj] = bv;
    }
    for (int k4 = 0; k4 < 64; k4++) {
        const int k0 = k4 * 4;
        float a[8][4];
#pragma unroll
        for (int pp = 0; pp < 8; pp++)
            *(float4*)&a[pp][0] = *(const float4*)&sr1[(pig * 8 + pp) * RUU + k0];
#pragma unroll
        for (int kk = 0; kk < 4; kk++) {
            float4 w0 = *(const float4*)&W2t[(size_t)(k0 + kk) * RUU + jg * 8];
            float4 w1_ = *(const float4*)&W2t[(size_t)(k0 + kk) * RUU + jg * 8 + 4];
#pragma unroll
            for (int pp = 0; pp < 8; pp++) {
                float av = a[pp][kk];
                accs[pp][0] = fmaf(av, w0.x, accs[pp][0]);
                accs[pp][1] = fmaf(av, w0.y, accs[pp][1]);
                accs[pp][2] = fmaf(av, w0.z, accs[pp][2]);
                accs[pp][3] = fmaf(av, w0.w, accs[pp][3]);
                accs[pp][4] = fmaf(av, w1_.x, accs[pp][4]);
                accs[pp][5] = fmaf(av, w1_.y, accs[pp][5]);
                accs[pp][6] = fmaf(av, w1_.z, accs[pp][6]);
                accs[pp][7] = fmaf(av, w1_.w, accs[pp][7]);
            }
        }
    }

    // epilogue: relu, W3 dot, shfl-reduce over jg (lanes&31), lane jg==0 stores
    float w3r[8];
#pragma unroll
    for (int c = 0; c < 2; c++)
        *(float4*)&w3r[c * 4] = *(const float4*)&W3[jg * 8 + c * 4];
    float val[8];
#pragma unroll
    for (int pp = 0; pp < 8; pp++) {
        float v = 0.f;
#pragma unroll
        for (int jj = 0; jj < 8; jj++) v = fmaf(w3r[jj], fmaxf(accs[pp][jj], 0.f), v);
        val[pp] = v;
    }
#pragma unroll
    for (int m = 1; m < 32; m <<= 1)
#pragma unroll
        for (int pp = 0; pp < 8; pp++) val[pp] += __shfl_xor(val[pp], m);
    if (jg == 0) {
        float b3v = b3[0];
#pragma unroll
        for (int pp = 0; pp < 8; pp++) {
            int p = p0 + pig * 8 + pp;
            if (p < NP) out[p] = val[pp] + b3v;
        }
    }
}

extern "C" void kernel_launch(void* const* d_in, const int* in_sizes, int n_in,
                              void* d_out, int out_size, void* d_ws, size_t ws_size,
                              hipStream_t stream) {
    const float* traffic  = (const float*)d_in[0];
    const float* packets  = (const float*)d_in[1];
    const float* tdp      = (const float*)d_in[2];
    const float* capacity = (const float*)d_in[3];
    const int* link_to_path = (const int*)d_in[4];
    const int* path_ids     = (const int*)d_in[5];
    const int* seq_path     = (const int*)d_in[6];
    const int* path_to_link = (const int*)d_in[7];
    const int* seq_links    = (const int*)d_in[8];
    const float* Wi_p = (const float*)d_in[11];
    const float* Wh_p = (const float*)d_in[12];
    const float* bi_p = (const float*)d_in[13];
    const float* bh_p = (const float*)d_in[14];
    const float* Wi_l = (const float*)d_in[15];
    const float* Wh_l = (const float*)d_in[16];
    const float* bi_l = (const float*)d_in[17];
    const float* bh_l = (const float*)d_in[18];
    const float* W1 = (const float*)d_in[19];
    const float* b1 = (const float*)d_in[20];
    const float* W2 = (const float*)d_in[21];
    const float* b2 = (const float*)d_in[22];
    const float* W3 = (const float*)d_in[23];
    const float* b3 = (const float*)d_in[24];
    float* out = (float*)d_out;

    float* path_state = (float*)d_ws;                  // NP*32 f32
    float* link_state = path_state + (size_t)NP * DD;  // NL*32
    float* w2t        = link_state + (size_t)NL * DD;  // 256*256
    int* lens     = (int*)(w2t + RUU * RUU);           // NP
    int* cnt      = lens + NP;                         // NL
    int* offs     = cnt + NL;                          // NL+1
    int* cursor   = offs + NL + 1;                     // NL
    int* csr_pids = cursor + NL;                       // NE

    k_init<<<(NP + 255) / 256, 256, 0, stream>>>(traffic, packets, tdp, capacity,
                                                 path_state, link_state, lens, cnt);
    k_lens<<<(NE + 255) / 256, 256, 0, stream>>>(path_ids, seq_path, lens);
    k_csr_count<<<(NE + 255) / 256, 256, 0, stream>>>(seq_links, cnt);
    k_csr_scan<<<1, 256, 0, stream>>>(cnt, offs, cursor);
    k_csr_fill<<<(NE + 255) / 256, 256, 0, stream>>>(seq_links, path_to_link,
                                                     cursor, csr_pids);
    k_w2t<<<RUU, RUU, 0, stream>>>(W2, w2t);
    for (int t = 0; t < TITERS; t++) {
        k_gru_paths<<<(NP + 4 * PPW - 1) / (4 * PPW), 256, 0, stream>>>(
            link_state, path_state, link_to_path, lens, Wi_p, Wh_p, bi_p, bh_p);
        k_links<<<(NL + 4 * LPW - 1) / (4 * LPW), 256, 0, stream>>>(
            path_state, link_state, offs, csr_pids, Wi_l, Wh_l, bi_l, bh_l);
    }
    k_readout<<<(NP + 63) / 64, 256, 0, stream>>>(path_state, out, W1, b1, w2t,
                                                  b2, W3, b3);
}

// Round 9
// 1371.227 us; speedup vs baseline: 2.1525x; 1.0774x over previous
//
#include <hip/hip_runtime.h>

#define NP 50000
#define NL 10000
#define PLEN 5
#define NE (NP * PLEN)
#define DD 32
#define RUU 256
#define TITERS 8
#define PPB 16   /* paths per block (4 per wave) */
#define LPB 16   /* links per block (4 per wave) */

__device__ __forceinline__ float sigmoidf_(float a) {
    return 1.0f / (1.0f + __expf(-a));
}
__device__ __forceinline__ float tanhf_(float a) {
    a = fminf(fmaxf(a, -15.0f), 15.0f);
    float t = __expf(2.0f * a);
    return (t - 1.0f) / (t + 1.0f);
}

__global__ __launch_bounds__(256) void k_init(
    const float* __restrict__ traffic, const float* __restrict__ packets,
    const float* __restrict__ tdp, const float* __restrict__ capacity,
    float* __restrict__ path_state, float* __restrict__ link_state,
    int* __restrict__ lens, int* __restrict__ cnt) {
    int i = blockIdx.x * 256 + threadIdx.x;
    if (i < NP) {
        float v[DD];
        v[0] = traffic[i];
        v[1] = packets[i];
#pragma unroll
        for (int k = 0; k < 12; k++) v[2 + k] = tdp[i * 12 + k];
#pragma unroll
        for (int k = 14; k < DD; k++) v[k] = 0.0f;
#pragma unroll
        for (int k = 0; k < DD; k++) path_state[i * DD + k] = v[k];
        lens[i] = 0;
    }
    if (i < NL) {
        link_state[i * DD] = capacity[i];
#pragma unroll
        for (int k = 1; k < DD; k++) link_state[i * DD + k] = 0.0f;
        cnt[i] = 0;
    }
}

__global__ __launch_bounds__(256) void k_lens(const int* __restrict__ path_ids,
                                              const int* __restrict__ seq_path,
                                              int* __restrict__ lens) {
    int e = blockIdx.x * 256 + threadIdx.x;
    if (e < NE) atomicMax(&lens[path_ids[e]], seq_path[e] + 1);
}

__global__ __launch_bounds__(256) void k_csr_count(const int* __restrict__ seq_links,
                                                   int* __restrict__ cnt) {
    int e = blockIdx.x * 256 + threadIdx.x;
    if (e < NE) atomicAdd(&cnt[seq_links[e]], 1);
}

__global__ __launch_bounds__(256) void k_csr_scan(const int* __restrict__ cnt,
                                                  int* __restrict__ offs,
                                                  int* __restrict__ cursor) {
    __shared__ int ssum[256];
    const int tid = threadIdx.x;
    const int CH = 40;
    int base = tid * CH;
    int s = 0;
    for (int i = 0; i < CH; i++) {
        int idx = base + i;
        s += (idx < NL) ? cnt[idx] : 0;
    }
    ssum[tid] = s;
    __syncthreads();
    for (int off = 1; off < 256; off <<= 1) {
        int t = (tid >= off) ? ssum[tid - off] : 0;
        __syncthreads();
        ssum[tid] += t;
        __syncthreads();
    }
    int run = ssum[tid] - s;
    for (int i = 0; i < CH; i++) {
        int idx = base + i;
        if (idx < NL) {
            offs[idx] = run;
            cursor[idx] = run;
            run += cnt[idx];
        }
    }
    if (tid == 0) offs[NL] = ssum[255];
}

__global__ __launch_bounds__(256) void k_csr_fill(const int* __restrict__ seq_links,
                                                  const int* __restrict__ path_to_link,
                                                  int* __restrict__ cursor,
                                                  int* __restrict__ csr_pids) {
    int e = blockIdx.x * 256 + threadIdx.x;
    if (e < NE) {
        int l = seq_links[e];
        int slot = atomicAdd(&cursor[l], 1);
        csr_pids[slot] = path_to_link[e];
    }
}

__global__ __launch_bounds__(256) void k_w2t(const float* __restrict__ W2,
                                             float* __restrict__ W2t) {
    int j = blockIdx.x, k = threadIdx.x;
    W2t[k * RUU + j] = W2[j * RUU + k];
}

// Path GRU, phase-split. Phase 1: gi = x@Wi^T + bi into LDS (Wi in 48 VGPRs).
// Phase 2: recurrence with Wh reusing the same registers.
// ALL LDS writes unconditional (both halves store bitwise-identical values);
// __syncthreads() at the phase boundary as a hard LDS fence.
__global__ __launch_bounds__(256, 4) void k_gru_paths(
    const float* __restrict__ link_state, float* __restrict__ path_state,
    const int* __restrict__ link_to_path, const int* __restrict__ lens,
    const float* __restrict__ Wi, const float* __restrict__ Wh,
    const float* __restrict__ bi, const float* __restrict__ bh) {
    __shared__ float gi[PPB * PLEN * 96];   // 30720 B
    __shared__ float hbuf[4][DD];           // 512 B
    const int tid = threadIdx.x;
    const int wave = tid >> 6;
    const int lane = tid & 63;
    const int d = lane & 31;
    const int half = lane >> 5;
    const int pl0 = wave * 4;
    const int pbase = blockIdx.x * PPB;

    float w[3][16];
    // ---- Phase 1: input transform with Wi ----
#pragma unroll
    for (int g = 0; g < 3; g++) {
        const float* wp = &Wi[(g * 32 + d) * 32 + half * 16];
#pragma unroll
        for (int c = 0; c < 4; c++) *(float4*)&w[g][c * 4] = *(const float4*)&wp[c * 4];
    }
#pragma unroll
    for (int g = 0; g < 3; g++)
#pragma unroll
        for (int k = 0; k < 16; k++) asm volatile("" : "+v"(w[g][k]));
    {
        const float b0 = bi[d], b1_ = bi[d + 32], b2_ = bi[d + 64];
        for (int j = 0; j < 4; j++) {
            const int p = pbase + pl0 + j;
#pragma unroll
            for (int st = 0; st < PLEN; st++) {
                const int li = link_to_path[p * PLEN + st];
                float xk[16];
#pragma unroll
                for (int c = 0; c < 4; c++)
                    *(float4*)&xk[c * 4] =
                        *(const float4*)&link_state[li * DD + half * 16 + c * 4];
                float s0 = 0.f, s1 = 0.f, s2 = 0.f;
#pragma unroll
                for (int k = 0; k < 16; k++) {
                    s0 = fmaf(xk[k], w[0][k], s0);
                    s1 = fmaf(xk[k], w[1][k], s1);
                    s2 = fmaf(xk[k], w[2][k], s2);
                }
                s0 += __shfl_xor(s0, 32);
                s1 += __shfl_xor(s1, 32);
                s2 += __shfl_xor(s2, 32);
                // both halves write identical values (commutative add -> same bits)
                float* gp = &gi[((pl0 + j) * PLEN + st) * 96];
                gp[d]      = s0 + b0;
                gp[d + 32] = s1 + b1_;
                gp[d + 64] = s2 + b2_;
            }
        }
    }
    __syncthreads();   // phase fence (no early exits: NP % PPB == 0)

    // ---- Phase 2: recurrence with Wh (register reuse) ----
#pragma unroll
    for (int g = 0; g < 3; g++) {
        const float* wp = &Wh[(g * 32 + d) * 32 + half * 16];
#pragma unroll
        for (int c = 0; c < 4; c++) *(float4*)&w[g][c * 4] = *(const float4*)&wp[c * 4];
    }
#pragma unroll
    for (int g = 0; g < 3; g++)
#pragma unroll
        for (int k = 0; k < 16; k++) asm volatile("" : "+v"(w[g][k]));
    const float bh0 = bh[d], bh1 = bh[d + 32], bh2 = bh[d + 64];

    for (int j = 0; j < 4; j++) {
        const int p = pbase + pl0 + j;
        const int len = lens[p];
        float hd = path_state[p * DD + d];
        float hk[16];
#pragma unroll
        for (int c = 0; c < 4; c++)
            *(float4*)&hk[c * 4] = *(const float4*)&path_state[p * DD + half * 16 + c * 4];
#pragma unroll
        for (int st = 0; st < PLEN; st++) {
            float hr = 0.f, hz = 0.f, hn = 0.f;
#pragma unroll
            for (int k = 0; k < 16; k++) {
                hr = fmaf(hk[k], w[0][k], hr);
                hz = fmaf(hk[k], w[1][k], hz);
                hn = fmaf(hk[k], w[2][k], hn);
            }
            hr += __shfl_xor(hr, 32);
            hz += __shfl_xor(hz, 32);
            hn += __shfl_xor(hn, 32);
            const float* gp = &gi[((pl0 + j) * PLEN + st) * 96];
            float gir = gp[d], giz = gp[d + 32], gin = gp[d + 64];
            float r = sigmoidf_(gir + hr + bh0);
            float z = sigmoidf_(giz + hz + bh1);
            float n = tanhf_(gin + r * (hn + bh2));
            float hnew = (1.0f - z) * n + z * hd;
            hd = (st < len) ? hnew : hd;
            hbuf[wave][d] = hd;   // unconditional (round-6-proven pattern)
#pragma unroll
            for (int c = 0; c < 4; c++)
                *(float4*)&hk[c * 4] = *(const float4*)&hbuf[wave][half * 16 + c * 4];
        }
        if (half == 0) path_state[p * DD + d] = hd;
    }
}

// Link update, 3-phase: gather -> gi (Wi) -> gh+combine (Wh).
// Unconditional LDS writes + barriers at phase boundaries.
__global__ __launch_bounds__(256, 4) void k_links(
    const float* __restrict__ path_state, float* __restrict__ link_state,
    const int* __restrict__ offs, const int* __restrict__ csr_pids,
    const float* __restrict__ Wi, const float* __restrict__ Wh,
    const float* __restrict__ bi, const float* __restrict__ bh) {
    __shared__ float xsum[4][4][DD];     // 2 KB
    __shared__ float gil[4][4][96];      // 6 KB
    const int tid = threadIdx.x;
    const int wave = tid >> 6;
    const int lane = tid & 63;
    const int d = lane & 31;
    const int half = lane >> 5;
    const int lbase = blockIdx.x * LPB + wave * 4;

    // Phase A: gather path_state sums (halves split edges)
    for (int j = 0; j < 4; j++) {
        const int l = lbase + j;
        const int beg = offs[l], end = offs[l + 1];
        float xv = 0.f;
        int t = beg + half;
        int pid = (t < end) ? csr_pids[t] : 0;
        while (t < end) {
            int t2 = t + 2;
            int pid2 = (t2 < end) ? csr_pids[t2] : 0;
            xv += path_state[pid * DD + d];
            pid = pid2;
            t = t2;
        }
        xv += __shfl_xor(xv, 32);
        xsum[wave][j][d] = xv;   // unconditional, identical bits both halves
    }
    __syncthreads();

    float w[3][16];
    // Phase B: gi = x@Wi^T + bi
#pragma unroll
    for (int g = 0; g < 3; g++) {
        const float* wp = &Wi[(g * 32 + d) * 32 + half * 16];
#pragma unroll
        for (int c = 0; c < 4; c++) *(float4*)&w[g][c * 4] = *(const float4*)&wp[c * 4];
    }
#pragma unroll
    for (int g = 0; g < 3; g++)
#pragma unroll
        for (int k = 0; k < 16; k++) asm volatile("" : "+v"(w[g][k]));
    {
        const float b0 = bi[d], b1_ = bi[d + 32], b2_ = bi[d + 64];
        for (int j = 0; j < 4; j++) {
            float xk[16];
#pragma unroll
            for (int c = 0; c < 4; c++)
                *(float4*)&xk[c * 4] = *(const float4*)&xsum[wave][j][half * 16 + c * 4];
            float s0 = 0.f, s1 = 0.f, s2 = 0.f;
#pragma unroll
            for (int k = 0; k < 16; k++) {
                s0 = fmaf(xk[k], w[0][k], s0);
                s1 = fmaf(xk[k], w[1][k], s1);
                s2 = fmaf(xk[k], w[2][k], s2);
            }
            s0 += __shfl_xor(s0, 32);
            s1 += __shfl_xor(s1, 32);
            s2 += __shfl_xor(s2, 32);
            gil[wave][j][d]      = s0 + b0;
            gil[wave][j][d + 32] = s1 + b1_;
            gil[wave][j][d + 64] = s2 + b2_;
        }
    }
    __syncthreads();

    // Phase C: gh with Wh (register reuse), combine, write back
#pragma unroll
    for (int g = 0; g < 3; g++) {
        const float* wp = &Wh[(g * 32 + d) * 32 + half * 16];
#pragma unroll
        for (int c = 0; c < 4; c++) *(float4*)&w[g][c * 4] = *(const float4*)&wp[c * 4];
    }
#pragma unroll
    for (int g = 0; g < 3; g++)
#pragma unroll
        for (int k = 0; k < 16; k++) asm volatile("" : "+v"(w[g][k]));
    const float bh0 = bh[d], bh1 = bh[d + 32], bh2 = bh[d + 64];
    for (int j = 0; j < 4; j++) {
        const int l = lbase + j;
        float hd = link_state[l * DD + d];
        float hk[16];
#pragma unroll
        for (int c = 0; c < 4; c++)
            *(float4*)&hk[c * 4] = *(const float4*)&link_state[l * DD + half * 16 + c * 4];
        float hr = 0.f, hz = 0.f, hn = 0.f;
#pragma unroll
        for (int k = 0; k < 16; k++) {
            hr = fmaf(hk[k], w[0][k], hr);
            hz = fmaf(hk[k], w[1][k], hz);
            hn = fmaf(hk[k], w[2][k], hn);
        }
        hr += __shfl_xor(hr, 32);
        hz += __shfl_xor(hz, 32);
        hn += __shfl_xor(hn, 32);
        float gir = gil[wave][j][d], giz = gil[wave][j][d + 32], gin = gil[wave][j][d + 64];
        float r = sigmoidf_(gir + hr + bh0);
        float z = sigmoidf_(giz + hz + bh1);
        float n = tanhf_(gin + r * (hn + bh2));
        float hnew = (1.0f - z) * n + z * hd;
        if (half == 0) link_state[l * DD + d] = hnew;
    }
}

// Readout: round-7 verbatim (known pass). 64 paths/block, LDS 64KB, 2 blk/CU.
__global__ __launch_bounds__(256, 2) void k_readout(
    const float* __restrict__ path_state, float* __restrict__ out,
    const float* __restrict__ W1, const float* __restrict__ b1,
    const float* __restrict__ W2t, const float* __restrict__ b2,
    const float* __restrict__ W3, const float* __restrict__ b3) {
    __shared__ float sr1[64 * RUU];      // 64 KB
    const int tid = threadIdx.x;
    const int p0 = blockIdx.x * 64;

    float w1r[DD];
#pragma unroll
    for (int c = 0; c < 8; c++)
        *(float4*)&w1r[c * 4] = *(const float4*)&W1[tid * DD + c * 4];
    float bb1 = b1[tid];

#pragma unroll 2
    for (int m = 0; m < 64; m++) {
        int p = p0 + m;
        if (p >= NP) p = NP - 1;
        const float4* xr = (const float4*)&path_state[(size_t)p * DD];
        float acc = bb1;
#pragma unroll
        for (int c = 0; c < 8; c++) {
            float4 xv = xr[c];
            acc = fmaf(xv.x, w1r[c * 4 + 0], fmaf(xv.y, w1r[c * 4 + 1],
                  fmaf(xv.z, w1r[c * 4 + 2], fmaf(xv.w, w1r[c * 4 + 3], acc))));
        }
        sr1[m * RUU + tid] = fmaxf(acc, 0.0f);
    }
    __syncthreads();

    const int pig = tid >> 5;
    const int jg  = tid & 31;
    float accs[8][8];
#pragma unroll
    for (int jj = 0; jj < 8; jj++) {
        float bv = b2[jg * 8 + jj];
#pragma unroll
        for (int pp = 0; pp < 8; pp++) accs[pp][jj] = bv;
    }
    for (int k4 = 0; k4 < 64; k4++) {
        const int k0 = k4 * 4;
        float a[8][4];
#pragma unroll
        for (int pp = 0; pp < 8; pp++)
            *(float4*)&a[pp][0] = *(const float4*)&sr1[(pig * 8 + pp) * RUU + k0];
#pragma unroll
        for (int kk = 0; kk < 4; kk++) {
            float4 w0 = *(const float4*)&W2t[(size_t)(k0 + kk) * RUU + jg * 8];
            float4 w1_ = *(const float4*)&W2t[(size_t)(k0 + kk) * RUU + jg * 8 + 4];
#pragma unroll
            for (int pp = 0; pp < 8; pp++) {
                float av = a[pp][kk];
                accs[pp][0] = fmaf(av, w0.x, accs[pp][0]);
                accs[pp][1] = fmaf(av, w0.y, accs[pp][1]);
                accs[pp][2] = fmaf(av, w0.z, accs[pp][2]);
                accs[pp][3] = fmaf(av, w0.w, accs[pp][3]);
                accs[pp][4] = fmaf(av, w1_.x, accs[pp][4]);
                accs[pp][5] = fmaf(av, w1_.y, accs[pp][5]);
                accs[pp][6] = fmaf(av, w1_.z, accs[pp][6]);
                accs[pp][7] = fmaf(av, w1_.w, accs[pp][7]);
            }
        }
    }

    float w3r[8];
#pragma unroll
    for (int c = 0; c < 2; c++)
        *(float4*)&w3r[c * 4] = *(const float4*)&W3[jg * 8 + c * 4];
    float val[8];
#pragma unroll
    for (int pp = 0; pp < 8; pp++) {
        float v = 0.f;
#pragma unroll
        for (int jj = 0; jj < 8; jj++) v = fmaf(w3r[jj], fmaxf(accs[pp][jj], 0.f), v);
        val[pp] = v;
    }
#pragma unroll
    for (int m = 1; m < 32; m <<= 1)
#pragma unroll
        for (int pp = 0; pp < 8; pp++) val[pp] += __shfl_xor(val[pp], m);
    if (jg == 0) {
        float b3v = b3[0];
#pragma unroll
        for (int pp = 0; pp < 8; pp++) {
            int p = p0 + pig * 8 + pp;
            if (p < NP) out[p] = val[pp] + b3v;
        }
    }
}

extern "C" void kernel_launch(void* const* d_in, const int* in_sizes, int n_in,
                              void* d_out, int out_size, void* d_ws, size_t ws_size,
                              hipStream_t stream) {
    const float* traffic  = (const float*)d_in[0];
    const float* packets  = (const float*)d_in[1];
    const float* tdp      = (const float*)d_in[2];
    const float* capacity = (const float*)d_in[3];
    const int* link_to_path = (const int*)d_in[4];
    const int* path_ids     = (const int*)d_in[5];
    const int* seq_path     = (const int*)d_in[6];
    const int* path_to_link = (const int*)d_in[7];
    const int* seq_links    = (const int*)d_in[8];
    const float* Wi_p = (const float*)d_in[11];
    const float* Wh_p = (const float*)d_in[12];
    const float* bi_p = (const float*)d_in[13];
    const float* bh_p = (const float*)d_in[14];
    const float* Wi_l = (const float*)d_in[15];
    const float* Wh_l = (const float*)d_in[16];
    const float* bi_l = (const float*)d_in[17];
    const float* bh_l = (const float*)d_in[18];
    const float* W1 = (const float*)d_in[19];
    const float* b1 = (const float*)d_in[20];
    const float* W2 = (const float*)d_in[21];
    const float* b2 = (const float*)d_in[22];
    const float* W3 = (const float*)d_in[23];
    const float* b3 = (const float*)d_in[24];
    float* out = (float*)d_out;

    float* path_state = (float*)d_ws;                  // NP*32 f32
    float* link_state = path_state + (size_t)NP * DD;  // NL*32
    float* w2t        = link_state + (size_t)NL * DD;  // 256*256
    int* lens     = (int*)(w2t + RUU * RUU);           // NP
    int* cnt      = lens + NP;                         // NL
    int* offs     = cnt + NL;                          // NL+1
    int* cursor   = offs + NL + 1;                     // NL
    int* csr_pids = cursor + NL;                       // NE

    k_init<<<(NP + 255) / 256, 256, 0, stream>>>(traffic, packets, tdp, capacity,
                                                 path_state, link_state, lens, cnt);
    k_lens<<<(NE + 255) / 256, 256, 0, stream>>>(path_ids, seq_path, lens);
    k_csr_count<<<(NE + 255) / 256, 256, 0, stream>>>(seq_links, cnt);
    k_csr_scan<<<1, 256, 0, stream>>>(cnt, offs, cursor);
    k_csr_fill<<<(NE + 255) / 256, 256, 0, stream>>>(seq_links, path_to_link,
                                                     cursor, csr_pids);
    k_w2t<<<RUU, RUU, 0, stream>>>(W2, w2t);
    for (int t = 0; t < TITERS; t++) {
        k_gru_paths<<<NP / PPB, 256, 0, stream>>>(
            link_state, path_state, link_to_path, lens, Wi_p, Wh_p, bi_p, bh_p);
        k_links<<<NL / LPB, 256, 0, stream>>>(
            path_state, link_state, offs, csr_pids, Wi_l, Wh_l, bi_l, bh_l);
    }
    k_readout<<<(NP + 63) / 64, 256, 0, stream>>>(path_state, out, W1, b1,
                                                  w2t, b2, W3, b3);
}